// Round 8
// baseline (565.292 us; speedup 1.0000x reference)
//
#include <hip/hip_runtime.h>
#include <math.h>

#define O_N 5000
#define T_N 20000
#define D_ 128
#define H_ 512
#define L_ 5
#define G_ 64
#define NT_ 1152
#define NPRED 180

typedef unsigned short ushort_t;
typedef __attribute__((ext_vector_type(8))) __bf16 bf16x8;
typedef __attribute__((ext_vector_type(4))) float f32x4;

__device__ inline float bf2f(ushort_t u) {
    union { unsigned u32; float f; } cv; cv.u32 = ((unsigned)u) << 16; return cv.f;
}
__device__ inline ushort_t f2bf(float f) {
    union { float f; unsigned u; } cv; cv.f = f;
    unsigned x = cv.u;
    unsigned r = x + 0x7FFFu + ((x >> 16) & 1u);
    return (ushort_t)(r >> 16);
}

__device__ inline void gload16(const void* g, void* l) {
    __builtin_amdgcn_global_load_lds(
        (const __attribute__((address_space(1))) unsigned int*)g,
        (__attribute__((address_space(3))) unsigned int*)l,
        16, 0, 0);
}

// ---------------- MFMA GEMM: C = relu(A @ Bt + bias) ----------------
// 128x128 tile, 4 waves, BK=32, 16x16x32 bf16 MFMA, fp32 accum.
// TRIPLE-buffered LDS, ONE barrier per K-step, counted vmcnt:
//   top of step t: vmcnt(4) (stage t landed) + s_barrier.
//   The barrier also proves every wave's step t-1 ds_reads retired
//   (MFMA issue requires the compiler's lgkmcnt wait), so staging
//   t+2 into buf[(t-1)%3] right after the barrier is WAR-safe with
//   no second barrier. Final step peeled with vmcnt(0).
// LDS swizzle: phys 16B-chunk = logical ^ ((row>>1)&3) on global source
// (gload_lds dest is linear) and on ds_read addrs.
// Epilogue: C bounced through LDS -> 16B coalesced stores.
// Grid: 1D, XCD-bijective chunk swizzle (m204), N-fastest inside chunk.
template<int GATHER, int WRITE_F32>
__global__ __launch_bounds__(256)
void mfma_gemm(const ushort_t* __restrict__ A,
               const ushort_t* __restrict__ Bt,
               const float* __restrict__ bias,
               ushort_t* __restrict__ Cb,
               float* __restrict__ Cf,
               int M, int N, int K, int ldc, int ntiles,
               const int* __restrict__ triples,
               const ushort_t* __restrict__ ovb,
               const ushort_t* __restrict__ P, int pstride, int pmap)
{
    __shared__ __align__(16) ushort_t smem[24576];   // A0|A1|A2|B0|B1|B2, 48 KB

    const int tid  = threadIdx.x;
    const int lane = tid & 63;
    const int wid  = tid >> 6;
    const int wm   = wid & 1;
    const int wn   = wid >> 1;

    // XCD-bijective swizzle + N-fastest decomposition
    const int nwg = gridDim.x;
    const int q = nwg >> 3, r = nwg & 7;
    const int xcd = blockIdx.x & 7, i8 = blockIdx.x >> 3;
    const int lid = (xcd < r ? xcd * (q + 1) : r * (q + 1) + (xcd - r) * q) + i8;
    const int bm = (lid / ntiles) * 128;
    const int bn = (lid % ntiles) * 128;

    // staging geometry: 16B unit u; two issues per wave per tile
    const int u0 = wid * 64 + lane;
    const int u1 = u0 + 256;
    const int r0 = u0 >> 2;
    const int r1 = u1 >> 2;
    const int ks0 = (((u0 & 3) ^ ((r0 >> 1) & 3)) << 3);   // logical k elem offset
    const int ks1 = (((u1 & 3) ^ ((r1 >> 1) & 3)) << 3);

    const int ga0 = min(bm + r0, M - 1);
    const int ga1 = min(bm + r1, M - 1);
    int s0 = 0, o0 = 0, p0 = 0, s1 = 0, o1 = 0, p1 = 0;
    if (GATHER) {
        s0 = triples[ga0 * 3];  p0 = pmap ? triples[ga0 * 3 + 1] : ga0;  o0 = triples[ga0 * 3 + 2];
        s1 = triples[ga1 * 3];  p1 = pmap ? triples[ga1 * 3 + 1] : ga1;  o1 = triples[ga1 * 3 + 2];
    }
    const int gb0 = bn + r0;
    const int gb1 = bn + r1;

    // fragment LDS read offsets (elems, buffer-relative), K-step invariant
    int offA[4], offB[4];
    #pragma unroll
    for (int i = 0; i < 4; ++i) {
        int ra = wm * 64 + i * 16 + (lane & 15);
        offA[i] = (ra * 4 + ((lane >> 4) ^ ((ra >> 1) & 3))) << 3;
        int rb = wn * 64 + i * 16 + (lane & 15);
        offB[i] = (rb * 4 + ((lane >> 4) ^ ((rb >> 1) & 3))) << 3;
    }

    auto stage = [&](int k0, int buf) {
        ushort_t* Ab = smem + buf * 4096;
        ushort_t* Bb = smem + 12288 + buf * 4096;
        const ushort_t *gA0p, *gA1p;
        if (GATHER) {
            int k = k0 + ks0;
            gA0p = (k < 128) ? (ovb + (size_t)s0 * D_ + k)
                 : (k < 256) ? (P + (size_t)p0 * pstride + (k - 128))
                             : (ovb + (size_t)o0 * D_ + (k - 256));
            k = k0 + ks1;
            gA1p = (k < 128) ? (ovb + (size_t)s1 * D_ + k)
                 : (k < 256) ? (P + (size_t)p1 * pstride + (k - 128))
                             : (ovb + (size_t)o1 * D_ + (k - 256));
        } else {
            gA0p = A + (size_t)ga0 * K + k0 + ks0;
            gA1p = A + (size_t)ga1 * K + k0 + ks1;
        }
        gload16(gA0p, Ab + wid * 512);
        gload16(gA1p, Ab + 2048 + wid * 512);
        gload16(Bt + (size_t)gb0 * K + k0 + ks0, Bb + wid * 512);
        gload16(Bt + (size_t)gb1 * K + k0 + ks1, Bb + 2048 + wid * 512);
    };

    f32x4 acc[4][4] = {};

    const int nt = K >> 5;          // 12 or 16 here
    stage(0, 0);
    stage(32, 1);                   // 8 loads/wave in flight

    int rb = 0;                     // read buffer for tile t
    for (int t = 0; t < nt; ++t) {
        if (t < nt - 1) {
            asm volatile("s_waitcnt vmcnt(4)" ::: "memory");
        } else {
            asm volatile("s_waitcnt vmcnt(0)" ::: "memory");
        }
        __builtin_amdgcn_s_barrier();
        __builtin_amdgcn_sched_barrier(0);
        if (t + 2 < nt) {
            int sb = rb + 2; if (sb >= 3) sb -= 3;   // == (t+2)%3 == (t-1)%3 slot
            stage((t + 2) << 5, sb);
        }
        const ushort_t* Ar = smem + rb * 4096;
        const ushort_t* Br = smem + 12288 + rb * 4096;
        bf16x8 av[4], bv[4];
        #pragma unroll
        for (int i = 0; i < 4; ++i) av[i] = *(const bf16x8*)(Ar + offA[i]);
        #pragma unroll
        for (int i = 0; i < 4; ++i) bv[i] = *(const bf16x8*)(Br + offB[i]);
        __builtin_amdgcn_s_setprio(1);
        #pragma unroll
        for (int mi = 0; mi < 4; ++mi)
            #pragma unroll
            for (int ni = 0; ni < 4; ++ni)
                acc[mi][ni] = __builtin_amdgcn_mfma_f32_16x16x32_bf16(
                    av[mi], bv[ni], acc[mi][ni], 0, 0, 0);
        __builtin_amdgcn_s_setprio(0);
        rb = (rb == 2) ? 0 : rb + 1;
    }
    __syncthreads();   // all waves done with smem buffers -> epilogue reuse

    if (WRITE_F32) {
        // last-layer GEMM4: only the f32 copy is consumed downstream
        #pragma unroll
        for (int ni = 0; ni < 4; ++ni) {
            int col = bn + wn * 64 + ni * 16 + (lane & 15);
            float bz = bias[col];
            #pragma unroll
            for (int mi = 0; mi < 4; ++mi) {
                int rowb = bm + wm * 64 + mi * 16 + ((lane >> 4) << 2);
                #pragma unroll
                for (int rr = 0; rr < 4; ++rr) {
                    int row = rowb + rr;
                    if (row < M) {
                        float v = fmaxf(acc[mi][ni][rr] + bz, 0.0f);
                        Cf[(size_t)row * ldc + col] = v;
                    }
                }
            }
        }
    } else {
        // LDS-bounce epilogue: per-wave 64x64 bf16 tile, 16B coalesced stores
        ushort_t* cst = smem + wid * 4096;
        #pragma unroll
        for (int ni = 0; ni < 4; ++ni) {
            int col = ni * 16 + (lane & 15);
            float bz = bias[bn + wn * 64 + col];
            #pragma unroll
            for (int mi = 0; mi < 4; ++mi) {
                int rowb = mi * 16 + ((lane >> 4) << 2);
                #pragma unroll
                for (int rr = 0; rr < 4; ++rr) {
                    float v = fmaxf(acc[mi][ni][rr] + bz, 0.0f);
                    cst[(rowb + rr) * 64 + col] = f2bf(v);
                }
            }
        }
        #pragma unroll
        for (int pp = 0; pp < 8; ++pp) {
            int wrow = pp * 8 + (lane >> 3);
            int grow = bm + wm * 64 + wrow;
            if (grow < M) {
                float4 v = *(const float4*)(cst + wrow * 64 + (lane & 7) * 8);
                *(float4*)(&Cb[(size_t)grow * ldc + bn + wn * 64 + (lane & 7) * 8]) = v;
            }
        }
    }
}

// ---------------- fused precompute: 4 weight transposes + embs + cnt zero ----
__global__ __launch_bounds__(256)
void precompute_kernel(const float* __restrict__ n1w1, const float* __restrict__ n1w2,
                       const float* __restrict__ n2w1, const float* __restrict__ n2w2,
                       ushort_t* __restrict__ w1t, ushort_t* __restrict__ w2t,
                       ushort_t* __restrict__ w3t, ushort_t* __restrict__ w4t,
                       const int* __restrict__ objs, const float* __restrict__ obj_emb,
                       const float* __restrict__ pred_emb,
                       ushort_t* __restrict__ ovb, ushort_t* __restrict__ predb,
                       int* __restrict__ cnt)
{
    int b = blockIdx.x;
    if (b < 5440) {
        int l = b / 1088, r = b % 1088;
        const float* src; ushort_t* dst; int K, N, n0, k0;
        if (r < 192)       { src = n1w1; dst = w1t; K = 384; N = 512;  n0 = (r % 16) * 32; k0 = (r / 16) * 32; }
        else if (r < 768)  { r -= 192;  src = n1w2; dst = w2t; K = 512; N = 1152; n0 = (r % 36) * 32; k0 = (r / 36) * 32; }
        else if (r < 1024) { r -= 768;  src = n2w1; dst = w3t; K = 512; N = 512;  n0 = (r % 16) * 32; k0 = (r / 16) * 32; }
        else               { r -= 1024; src = n2w2; dst = w4t; K = 512; N = 128;  n0 = (r % 4) * 32;  k0 = (r / 4) * 32; }
        __shared__ float t[32][33];
        const float* s = src + (size_t)l * K * N;
        ushort_t*    d = dst + (size_t)l * N * K;
        int rr = threadIdx.x >> 5, c = threadIdx.x & 31;
        #pragma unroll
        for (int j = 0; j < 4; ++j)
            t[rr + j * 8][c] = s[(size_t)(k0 + rr + j * 8) * N + n0 + c];
        __syncthreads();
        #pragma unroll
        for (int j = 0; j < 4; ++j)
            d[(size_t)(n0 + rr + j * 8) * K + k0 + c] = f2bf(t[c][rr + j * 8]);
    } else if (b < 8030) {
        int i = (b - 5440) * 256 + threadIdx.x;
        if (i < O_N * D_) ovb[i] = f2bf(obj_emb[(size_t)objs[i >> 7] * D_ + (i & 127)]);
        int j = i - O_N * D_;
        if (j >= 0 && j < NPRED * D_) predb[j] = f2bf(pred_emb[j]);
    } else {
        int i = (b - 8030) * 256 + threadIdx.x;
        if (i < O_N) cnt[i] = 0;
    }
}

// ---------------- CSR build (loop-invariant) ----------------
__global__ void hist_kernel(const int* __restrict__ triples, int* __restrict__ cnt)
{
    int t = blockIdx.x * blockDim.x + threadIdx.x;
    if (t < T_N) {
        atomicAdd(&cnt[triples[t * 3]], 1);
        atomicAdd(&cnt[triples[t * 3 + 2]], 1);
    }
}

__global__ void scan_kernel(const int* __restrict__ cnt, int* __restrict__ off,
                            int* __restrict__ cursor)
{
    __shared__ int buf[256];
    __shared__ int base;
    int tid = threadIdx.x;
    if (tid == 0) base = 0;
    __syncthreads();
    for (int ch = 0; ch < O_N; ch += 256) {
        int v = (ch + tid < O_N) ? cnt[ch + tid] : 0;
        buf[tid] = v;
        __syncthreads();
        for (int s = 1; s < 256; s <<= 1) {
            int tmp = (tid >= s) ? buf[tid - s] : 0;
            __syncthreads();
            buf[tid] += tmp;
            __syncthreads();
        }
        int excl = base + buf[tid] - v;
        if (ch + tid < O_N) { off[ch + tid] = excl; cursor[ch + tid] = excl; }
        __syncthreads();
        if (tid == 0) base += buf[255];
        __syncthreads();
    }
    if (tid == 0) off[O_N] = base;
}

__global__ void fill_kernel(const int* __restrict__ triples, int* __restrict__ cursor,
                            int* __restrict__ entries)
{
    int t = blockIdx.x * blockDim.x + threadIdx.x;
    if (t < T_N) {
        int s = triples[t * 3], o = triples[t * 3 + 2];
        entries[atomicAdd(&cursor[s], 1)] = t * 2;
        entries[atomicAdd(&cursor[o], 1)] = t * 2 + 1;
    }
}

// ---------------- scatter-mean via CSR gather, 1/count fused ----------------
__global__ void pooled_kernel(const ushort_t* __restrict__ newt,
                              const int* __restrict__ entries,
                              const int* __restrict__ off,
                              ushort_t* __restrict__ pooled)
{
    int i = blockIdx.x, tid = threadIdx.x;   // 128 threads, 4 d each
    int st = off[i], en = off[i + 1];
    float a0 = 0.f, a1 = 0.f, a2 = 0.f, a3 = 0.f;
    for (int e = st; e < en; ++e) {
        int ent = entries[e];
        const ushort_t* row = newt + (size_t)(ent >> 1) * NT_ + (ent & 1) * 640 + tid * 4;
        ushort4 v = *(const ushort4*)row;
        a0 += bf2f(v.x); a1 += bf2f(v.y); a2 += bf2f(v.z); a3 += bf2f(v.w);
    }
    int c = en - st; if (c < 1) c = 1;
    float sc = 1.0f / (float)c;
    ushort4 outv;
    outv.x = f2bf(a0 * sc); outv.y = f2bf(a1 * sc);
    outv.z = f2bf(a2 * sc); outv.w = f2bf(a3 * sc);
    *(ushort4*)(pooled + (size_t)i * H_ + tid * 4) = outv;
}

// ---------------- final graph pooling ----------------
__global__ void scores_kernel(const float* __restrict__ ov,
                              const float* __restrict__ att_w,
                              const float* __restrict__ att_b,
                              float* __restrict__ scores)
{
    int gidx = blockIdx.x * blockDim.x + threadIdx.x;
    int obj = gidx >> 6;
    int lane = threadIdx.x & 63;
    if (obj >= O_N) return;
    const float* r = ov + (size_t)obj * D_;
    float v = r[lane] * att_w[lane] + r[lane + 64] * att_w[lane + 64];
    #pragma unroll
    for (int off = 32; off; off >>= 1) v += __shfl_down(v, off);
    if (lane == 0) scores[obj] = v + att_b[0];
}

// one block per image: binary-search bounds in SORTED obj_to_img,
// then max / sum(exp) / weighted ov-sum, all block-local.
__global__ __launch_bounds__(256)
void seg_gvec_kernel(const float* __restrict__ scores, const float* __restrict__ ovf,
                     const int* __restrict__ obj_to_img, float* __restrict__ gvec)
{
    __shared__ float red[256];
    __shared__ float sm, sz;
    int g = blockIdx.x, tid = threadIdx.x;
    int lo = 0, hi = O_N;
    while (lo < hi) { int mid = (lo + hi) >> 1; if (obj_to_img[mid] < g) lo = mid + 1; else hi = mid; }
    int st = lo;
    hi = O_N;
    while (lo < hi) { int mid = (lo + hi) >> 1; if (obj_to_img[mid] <= g) lo = mid + 1; else hi = mid; }
    int en = lo;

    float lm = -1e30f;
    for (int i = st + tid; i < en; i += 256) lm = fmaxf(lm, scores[i]);
    red[tid] = lm; __syncthreads();
    for (int s = 128; s; s >>= 1) { if (tid < s) red[tid] = fmaxf(red[tid], red[tid + s]); __syncthreads(); }
    if (tid == 0) sm = red[0];
    __syncthreads();
    float m = sm;

    float lz = 0.f;
    for (int i = st + tid; i < en; i += 256) lz += expf(scores[i] - m);
    red[tid] = lz; __syncthreads();
    for (int s = 128; s; s >>= 1) { if (tid < s) red[tid] += red[tid + s]; __syncthreads(); }
    if (tid == 0) sz = fmaxf(red[0], 1e-30f);
    __syncthreads();
    float invz = 1.0f / sz;

    int d = tid & 127, half = tid >> 7;
    float acc = 0.f;
    for (int i = st + half; i < en; i += 2)
        acc += expf(scores[i] - m) * ovf[(size_t)i * D_ + d];
    red[tid] = acc; __syncthreads();
    if (tid < 128) gvec[(size_t)g * D_ + tid] = (red[tid] + red[tid + 128]) * invz;
}

__global__ void output_kernel(const float* __restrict__ ov, const float* __restrict__ gvec,
                              const int* __restrict__ obj_to_img, float* __restrict__ out)
{
    int idx = blockIdx.x * blockDim.x + threadIdx.x;
    if (idx >= O_N * 256) return;
    int i = idx >> 8, d = idx & 255;
    out[idx] = (d < 128) ? ov[(size_t)i * D_ + d]
                         : gvec[obj_to_img[i] * D_ + (d - 128)];
}

// ---------------- host launch ----------------
extern "C" void kernel_launch(void* const* d_in, const int* in_sizes, int n_in,
                              void* d_out, int out_size, void* d_ws, size_t ws_size,
                              hipStream_t stream)
{
    const int*   objs       = (const int*)d_in[0];
    const int*   triples    = (const int*)d_in[1];
    const int*   obj_to_img = (const int*)d_in[2];
    const float* obj_emb    = (const float*)d_in[3];
    const float* pred_emb   = (const float*)d_in[4];
    const float* n1w1       = (const float*)d_in[5];
    const float* n1b1       = (const float*)d_in[6];
    const float* n1w2       = (const float*)d_in[7];
    const float* n1b2       = (const float*)d_in[8];
    const float* n2w1       = (const float*)d_in[9];
    const float* n2b1       = (const float*)d_in[10];
    const float* n2w2       = (const float*)d_in[11];
    const float* n2b2       = (const float*)d_in[12];
    const float* att_w      = (const float*)d_in[13];
    const float* att_b      = (const float*)d_in[14];
    float* out = (float*)d_out;

    char* p = (char*)d_ws;
    auto carve = [&](size_t bytes) -> char* {
        char* r = p; p += (bytes + 255) & ~(size_t)255; return r;
    };
    ushort_t* w1t     = (ushort_t*)carve((size_t)L_ * 512 * 384 * 2);
    ushort_t* w2t     = (ushort_t*)carve((size_t)L_ * 1152 * 512 * 2);
    ushort_t* w3t     = (ushort_t*)carve((size_t)L_ * 512 * 512 * 2);
    ushort_t* w4t     = (ushort_t*)carve((size_t)L_ * 128 * 512 * 2);
    ushort_t* ovbA    = (ushort_t*)carve((size_t)O_N * D_ * 2);
    ushort_t* ovbB    = (ushort_t*)carve((size_t)O_N * D_ * 2);
    ushort_t* predb   = (ushort_t*)carve((size_t)NPRED * D_ * 2);
    ushort_t* hiddenb = (ushort_t*)carve((size_t)T_N * H_ * 2);
    ushort_t* newtb   = (ushort_t*)carve((size_t)T_N * NT_ * 2);
    ushort_t* pooledb = (ushort_t*)carve((size_t)O_N * H_ * 2);
    float*    ovf     = (float*)carve((size_t)O_N * D_ * 4);
    float*    scores  = (float*)carve((size_t)O_N * 4);
    float*    gvec    = (float*)carve((size_t)G_ * D_ * 4);
    int*      cnt     = (int*)carve((size_t)O_N * 4);
    int*      off     = (int*)carve((size_t)(O_N + 1) * 4);
    int*      cursor  = (int*)carve((size_t)O_N * 4);
    int*      entries = (int*)carve((size_t)2 * T_N * 4);

    // once-per-call pre-compute (fused) + CSR build
    precompute_kernel<<<8050, 256, 0, stream>>>(
        n1w1, n1w2, n2w1, n2w2, w1t, w2t, w3t, w4t,
        objs, obj_emb, pred_emb, ovbA, predb, cnt);
    hist_kernel<<<(T_N + 255) / 256, 256, 0, stream>>>(triples, cnt);
    scan_kernel<<<1, 256, 0, stream>>>(cnt, off, cursor);
    fill_kernel<<<(T_N + 255) / 256, 256, 0, stream>>>(triples, cursor, entries);

    ushort_t* ovcur = ovbA;
    ushort_t* ovnxt = ovbB;

    for (int l = 0; l < L_; ++l) {
        const ushort_t* Pl = (l == 0) ? predb : (newtb + H_);
        int pstr = (l == 0) ? D_ : NT_;
        int pmap = (l == 0) ? 1 : 0;

        // GEMM1: hidden = relu(concat(ov[s],pv,ov[o]) @ n1w1 + b1)   [20000 x 384 x 512]
        mfma_gemm<1, 0><<<157 * 4, 256, 0, stream>>>(
            nullptr, w1t + (size_t)l * 512 * 384, n1b1 + (size_t)l * H_,
            hiddenb, nullptr, T_N, 512, 384, H_, 4,
            triples, ovcur, Pl, pstr, pmap);

        // GEMM2: new_t = relu(hidden @ n1w2 + b2)                    [20000 x 512 x 1152]
        mfma_gemm<0, 0><<<157 * 9, 256, 0, stream>>>(
            hiddenb, w2t + (size_t)l * 1152 * 512, n1b2 + (size_t)l * NT_,
            newtb, nullptr, T_N, NT_, 512, NT_, 9,
            nullptr, nullptr, nullptr, 0, 0);

        // scatter-mean via CSR gather
        pooled_kernel<<<O_N, 128, 0, stream>>>(newtb, entries, off, pooledb);

        // GEMM3: h2 = relu(pooled @ n2w1 + b1)                       [5000 x 512 x 512]
        mfma_gemm<0, 0><<<40 * 4, 256, 0, stream>>>(
            pooledb, w3t + (size_t)l * 512 * 512, n2b1 + (size_t)l * H_,
            hiddenb, nullptr, O_N, 512, 512, H_, 4,
            nullptr, nullptr, nullptr, 0, 0);

        // GEMM4: new_ov = relu(h2 @ n2w2 + b2)                       [5000 x 512 x 128]
        if (l < L_ - 1) {
            mfma_gemm<0, 0><<<40 * 1, 256, 0, stream>>>(
                hiddenb, w4t + (size_t)l * 128 * 512, n2b2 + (size_t)l * D_,
                ovnxt, nullptr, O_N, 128, 512, D_, 1,
                nullptr, nullptr, nullptr, 0, 0);
        } else {
            mfma_gemm<0, 1><<<40 * 1, 256, 0, stream>>>(
                hiddenb, w4t + (size_t)l * 128 * 512, n2b2 + (size_t)l * D_,
                ovnxt, ovf, O_N, 128, 512, D_, 1,
                nullptr, nullptr, nullptr, 0, 0);
        }

        ushort_t* tmp = ovcur; ovcur = ovnxt; ovnxt = tmp;
    }

    // graph pooling (fp32 ov from last GEMM4)
    scores_kernel<<<(O_N * 64 + 255) / 256, 256, 0, stream>>>(ovf, att_w, att_b, scores);
    seg_gvec_kernel<<<G_, 256, 0, stream>>>(scores, ovf, obj_to_img, gvec);
    output_kernel<<<(O_N * 256 + 255) / 256, 256, 0, stream>>>(ovf, gvec, obj_to_img, out);
}

// Round 9
// 562.348 us; speedup vs baseline: 1.0052x; 1.0052x over previous
//
#include <hip/hip_runtime.h>
#include <math.h>

#define O_N 5000
#define T_N 20000
#define D_ 128
#define H_ 512
#define L_ 5
#define G_ 64
#define NT_ 1152
#define NPRED 180

typedef unsigned short ushort_t;
typedef __attribute__((ext_vector_type(8))) __bf16 bf16x8;
typedef __attribute__((ext_vector_type(4))) float f32x4;

__device__ inline float bf2f(ushort_t u) {
    union { unsigned u32; float f; } cv; cv.u32 = ((unsigned)u) << 16; return cv.f;
}
__device__ inline ushort_t f2bf(float f) {
    union { float f; unsigned u; } cv; cv.f = f;
    unsigned x = cv.u;
    unsigned r = x + 0x7FFFu + ((x >> 16) & 1u);
    return (ushort_t)(r >> 16);
}

__device__ inline void gload16(const void* g, void* l) {
    __builtin_amdgcn_global_load_lds(
        (const __attribute__((address_space(1))) unsigned int*)g,
        (__attribute__((address_space(3))) unsigned int*)l,
        16, 0, 0);
}

// ---------------- MFMA GEMM: C = relu(A @ Bt + bias) ----------------
// Tile BM x 128, BM in {128, 256}. threads = BM*2 (4 or 8 waves of 64).
// Wave grid: (BM/64) M-subtiles x 2 N-subtiles, each wave 64x64, BK=32.
// TRIPLE-buffered LDS, ONE barrier per K-step, counted vmcnt:
//   loads/wave/K-step = 4 (BM=128: A0,A1,B0,B1) or 3 (BM=256: A0,A1,B).
//   depth-2 prologue -> 8 (or 6) outstanding; in-loop wait vmcnt(4|3)
//   = oldest stage landed; barrier; stage(t+2) into buf[(t-1)%3]
//   (WAR-safe: all waves' t-1 ds_reads retired before their barrier
//   arrival, forced by the compiler's lgkmcnt before t-1's MFMAs).
//   Final step peeled with vmcnt(0).
// LDS swizzle: phys 16B-chunk = logical ^ ((row>>1)&3) on global source
// (gload_lds dest is linear) and on ds_read addrs.
// Epilogue: C bounced through LDS -> 16B coalesced stores.
// Grid: 1D, XCD-bijective chunk swizzle (m204), N-fastest inside chunk.
template<int BM, int GATHER, int WRITE_F32>
__global__ __launch_bounds__(BM * 2)
void mfma_gemm(const ushort_t* __restrict__ A,
               const ushort_t* __restrict__ Bt,
               const float* __restrict__ bias,
               ushort_t* __restrict__ Cb,
               float* __restrict__ Cf,
               int M, int N, int K, int ldc, int ntiles,
               const int* __restrict__ triples,
               const ushort_t* __restrict__ ovb,
               const ushort_t* __restrict__ P, int pstride, int pmap)
{
    constexpr int NW = BM / 32;               // waves: 128->4, 256->8
    constexpr int MW = BM / 64;               // M-subtiles
    constexpr int ABUF = BM * 32;             // A buffer elems
    constexpr int BBASE = 3 * ABUF;           // B buffers start (elems)
    constexpr int SMEMN = 3 * ABUF + 3 * 4096;
    __shared__ __align__(16) ushort_t smem[SMEMN];

    const int tid  = threadIdx.x;
    const int lane = tid & 63;
    const int wid  = tid >> 6;
    const int wm   = wid & (MW - 1);
    const int wn   = wid >> (MW == 2 ? 1 : 2);

    // XCD-bijective swizzle + N-fastest decomposition
    const int nwg = gridDim.x;
    const int q = nwg >> 3, r = nwg & 7;
    const int xcd = blockIdx.x & 7, i8 = blockIdx.x >> 3;
    const int lid = (xcd < r ? xcd * (q + 1) : r * (q + 1) + (xcd - r) * q) + i8;
    const int bm = (lid / ntiles) * BM;
    const int bn = (lid % ntiles) * 128;

    // staging geometry: 16B unit u; A issues 0,1; B issue(s)
    const int ua0 = wid * 64 + lane;            // A units [0, 64*NW)
    const int ua1 = ua0 + 64 * NW;              // A units [64NW, 128NW)
    const int ra0 = ua0 >> 2, ra1 = ua1 >> 2;   // A rows
    const int ksa0 = (((ua0 & 3) ^ ((ra0 >> 1) & 3)) << 3);
    const int ksa1 = (((ua1 & 3) ^ ((ra1 >> 1) & 3)) << 3);
    // B: BM=128 -> 2 issues (same u pattern); BM=256 -> 1 issue
    const int ub0 = wid * 64 + lane;
    const int rb0 = ub0 >> 2;
    const int ksb0 = (((ub0 & 3) ^ ((rb0 >> 1) & 3)) << 3);
    const int ub1 = ub0 + 256;                  // only used when BM==128
    const int rb1 = ub1 >> 2;
    const int ksb1 = (((ub1 & 3) ^ ((rb1 >> 1) & 3)) << 3);

    const int ga0 = min(bm + ra0, M - 1);
    const int ga1 = min(bm + ra1, M - 1);
    int s0 = 0, o0 = 0, p0 = 0, s1 = 0, o1 = 0, p1 = 0;
    if (GATHER) {
        s0 = triples[ga0 * 3];  p0 = pmap ? triples[ga0 * 3 + 1] : ga0;  o0 = triples[ga0 * 3 + 2];
        s1 = triples[ga1 * 3];  p1 = pmap ? triples[ga1 * 3 + 1] : ga1;  o1 = triples[ga1 * 3 + 2];
    }

    // fragment LDS read offsets (elems, buffer-relative), K-step invariant
    int offA[4], offB[4];
    #pragma unroll
    for (int i = 0; i < 4; ++i) {
        int ra = wm * 64 + i * 16 + (lane & 15);
        offA[i] = (ra * 4 + ((lane >> 4) ^ ((ra >> 1) & 3))) << 3;
        int rbq = wn * 64 + i * 16 + (lane & 15);
        offB[i] = (rbq * 4 + ((lane >> 4) ^ ((rbq >> 1) & 3))) << 3;
    }

    auto gatherA = [&](int k, int sx, int px, int ox) -> const ushort_t* {
        return (k < 128) ? (ovb + (size_t)sx * D_ + k)
             : (k < 256) ? (P + (size_t)px * pstride + (k - 128))
                         : (ovb + (size_t)ox * D_ + (k - 256));
    };

    auto stage = [&](int k0, int buf) {
        ushort_t* Ab = smem + buf * ABUF;
        ushort_t* Bb = smem + BBASE + buf * 4096;
        const ushort_t *gA0p, *gA1p;
        if (GATHER) {
            gA0p = gatherA(k0 + ksa0, s0, p0, o0);
            gA1p = gatherA(k0 + ksa1, s1, p1, o1);
        } else {
            gA0p = A + (size_t)ga0 * K + k0 + ksa0;
            gA1p = A + (size_t)ga1 * K + k0 + ksa1;
        }
        gload16(gA0p, Ab + wid * 512);
        gload16(gA1p, Ab + NW * 512 + wid * 512);
        gload16(Bt + (size_t)(bn + rb0) * K + k0 + ksb0, Bb + wid * 512);
        if (BM == 128)
            gload16(Bt + (size_t)(bn + rb1) * K + k0 + ksb1, Bb + 2048 + wid * 512);
    };

    f32x4 acc[4][4] = {};

    const int nt = K >> 5;          // 12 or 16 here
    stage(0, 0);
    stage(32, 1);

    int rb = 0;                     // read buffer for tile t
    for (int t = 0; t < nt; ++t) {
        if (t < nt - 1) {
            if (BM == 128) asm volatile("s_waitcnt vmcnt(4)" ::: "memory");
            else           asm volatile("s_waitcnt vmcnt(3)" ::: "memory");
        } else {
            asm volatile("s_waitcnt vmcnt(0)" ::: "memory");
        }
        __builtin_amdgcn_s_barrier();
        __builtin_amdgcn_sched_barrier(0);
        if (t + 2 < nt) {
            int sb = rb + 2; if (sb >= 3) sb -= 3;
            stage((t + 2) << 5, sb);
        }
        const ushort_t* Ar = smem + rb * ABUF;
        const ushort_t* Br = smem + BBASE + rb * 4096;
        bf16x8 av[4], bv[4];
        #pragma unroll
        for (int i = 0; i < 4; ++i) av[i] = *(const bf16x8*)(Ar + offA[i]);
        #pragma unroll
        for (int i = 0; i < 4; ++i) bv[i] = *(const bf16x8*)(Br + offB[i]);
        __builtin_amdgcn_s_setprio(1);
        #pragma unroll
        for (int mi = 0; mi < 4; ++mi)
            #pragma unroll
            for (int ni = 0; ni < 4; ++ni)
                acc[mi][ni] = __builtin_amdgcn_mfma_f32_16x16x32_bf16(
                    av[mi], bv[ni], acc[mi][ni], 0, 0, 0);
        __builtin_amdgcn_s_setprio(0);
        rb = (rb == 2) ? 0 : rb + 1;
    }
    __syncthreads();   // all waves done with smem buffers -> epilogue reuse

    if (WRITE_F32) {
        // last-layer GEMM4: only the f32 copy is consumed downstream
        #pragma unroll
        for (int ni = 0; ni < 4; ++ni) {
            int col = bn + wn * 64 + ni * 16 + (lane & 15);
            float bz = bias[col];
            #pragma unroll
            for (int mi = 0; mi < 4; ++mi) {
                int rowb = bm + wm * 64 + mi * 16 + ((lane >> 4) << 2);
                #pragma unroll
                for (int rr = 0; rr < 4; ++rr) {
                    int row = rowb + rr;
                    if (row < M) {
                        float v = fmaxf(acc[mi][ni][rr] + bz, 0.0f);
                        Cf[(size_t)row * ldc + col] = v;
                    }
                }
            }
        }
    } else {
        // LDS-bounce epilogue: per-wave 64x64 bf16 tile, 16B coalesced stores
        ushort_t* cst = smem + wid * 4096;
        #pragma unroll
        for (int ni = 0; ni < 4; ++ni) {
            int col = ni * 16 + (lane & 15);
            float bz = bias[bn + wn * 64 + col];
            #pragma unroll
            for (int mi = 0; mi < 4; ++mi) {
                int rowb = mi * 16 + ((lane >> 4) << 2);
                #pragma unroll
                for (int rr = 0; rr < 4; ++rr) {
                    float v = fmaxf(acc[mi][ni][rr] + bz, 0.0f);
                    cst[(rowb + rr) * 64 + col] = f2bf(v);
                }
            }
        }
        #pragma unroll
        for (int pp = 0; pp < 8; ++pp) {
            int wrow = pp * 8 + (lane >> 3);
            int grow = bm + wm * 64 + wrow;
            if (grow < M) {
                float4 v = *(const float4*)(cst + wrow * 64 + (lane & 7) * 8);
                *(float4*)(&Cb[(size_t)grow * ldc + bn + wn * 64 + (lane & 7) * 8]) = v;
            }
        }
    }
}

// ---------------- fused precompute: 4 weight transposes + embs + cnt zero ----
__global__ __launch_bounds__(256)
void precompute_kernel(const float* __restrict__ n1w1, const float* __restrict__ n1w2,
                       const float* __restrict__ n2w1, const float* __restrict__ n2w2,
                       ushort_t* __restrict__ w1t, ushort_t* __restrict__ w2t,
                       ushort_t* __restrict__ w3t, ushort_t* __restrict__ w4t,
                       const int* __restrict__ objs, const float* __restrict__ obj_emb,
                       const float* __restrict__ pred_emb,
                       ushort_t* __restrict__ ovb, ushort_t* __restrict__ predb,
                       int* __restrict__ cnt)
{
    int b = blockIdx.x;
    if (b < 5440) {
        int l = b / 1088, r = b % 1088;
        const float* src; ushort_t* dst; int K, N, n0, k0;
        if (r < 192)       { src = n1w1; dst = w1t; K = 384; N = 512;  n0 = (r % 16) * 32; k0 = (r / 16) * 32; }
        else if (r < 768)  { r -= 192;  src = n1w2; dst = w2t; K = 512; N = 1152; n0 = (r % 36) * 32; k0 = (r / 36) * 32; }
        else if (r < 1024) { r -= 768;  src = n2w1; dst = w3t; K = 512; N = 512;  n0 = (r % 16) * 32; k0 = (r / 16) * 32; }
        else               { r -= 1024; src = n2w2; dst = w4t; K = 512; N = 128;  n0 = (r % 4) * 32;  k0 = (r / 4) * 32; }
        __shared__ float t[32][33];
        const float* s = src + (size_t)l * K * N;
        ushort_t*    d = dst + (size_t)l * N * K;
        int rr = threadIdx.x >> 5, c = threadIdx.x & 31;
        #pragma unroll
        for (int j = 0; j < 4; ++j)
            t[rr + j * 8][c] = s[(size_t)(k0 + rr + j * 8) * N + n0 + c];
        __syncthreads();
        #pragma unroll
        for (int j = 0; j < 4; ++j)
            d[(size_t)(n0 + rr + j * 8) * K + k0 + c] = f2bf(t[c][rr + j * 8]);
    } else if (b < 8030) {
        int i = (b - 5440) * 256 + threadIdx.x;
        if (i < O_N * D_) ovb[i] = f2bf(obj_emb[(size_t)objs[i >> 7] * D_ + (i & 127)]);
        int j = i - O_N * D_;
        if (j >= 0 && j < NPRED * D_) predb[j] = f2bf(pred_emb[j]);
    } else {
        int i = (b - 8030) * 256 + threadIdx.x;
        if (i < O_N) cnt[i] = 0;
    }
}

// ---------------- CSR build (loop-invariant) ----------------
__global__ void hist_kernel(const int* __restrict__ triples, int* __restrict__ cnt)
{
    int t = blockIdx.x * blockDim.x + threadIdx.x;
    if (t < T_N) {
        atomicAdd(&cnt[triples[t * 3]], 1);
        atomicAdd(&cnt[triples[t * 3 + 2]], 1);
    }
}

__global__ void scan_kernel(const int* __restrict__ cnt, int* __restrict__ off,
                            int* __restrict__ cursor)
{
    __shared__ int buf[256];
    __shared__ int base;
    int tid = threadIdx.x;
    if (tid == 0) base = 0;
    __syncthreads();
    for (int ch = 0; ch < O_N; ch += 256) {
        int v = (ch + tid < O_N) ? cnt[ch + tid] : 0;
        buf[tid] = v;
        __syncthreads();
        for (int s = 1; s < 256; s <<= 1) {
            int tmp = (tid >= s) ? buf[tid - s] : 0;
            __syncthreads();
            buf[tid] += tmp;
            __syncthreads();
        }
        int excl = base + buf[tid] - v;
        if (ch + tid < O_N) { off[ch + tid] = excl; cursor[ch + tid] = excl; }
        __syncthreads();
        if (tid == 0) base += buf[255];
        __syncthreads();
    }
    if (tid == 0) off[O_N] = base;
}

__global__ void fill_kernel(const int* __restrict__ triples, int* __restrict__ cursor,
                            int* __restrict__ entries)
{
    int t = blockIdx.x * blockDim.x + threadIdx.x;
    if (t < T_N) {
        int s = triples[t * 3], o = triples[t * 3 + 2];
        entries[atomicAdd(&cursor[s], 1)] = t * 2;
        entries[atomicAdd(&cursor[o], 1)] = t * 2 + 1;
    }
}

// ---------------- scatter-mean via CSR gather, 1/count fused ----------------
__global__ void pooled_kernel(const ushort_t* __restrict__ newt,
                              const int* __restrict__ entries,
                              const int* __restrict__ off,
                              ushort_t* __restrict__ pooled)
{
    int i = blockIdx.x, tid = threadIdx.x;   // 128 threads, 4 d each
    int st = off[i], en = off[i + 1];
    float a0 = 0.f, a1 = 0.f, a2 = 0.f, a3 = 0.f;
    for (int e = st; e < en; ++e) {
        int ent = entries[e];
        const ushort_t* row = newt + (size_t)(ent >> 1) * NT_ + (ent & 1) * 640 + tid * 4;
        ushort4 v = *(const ushort4*)row;
        a0 += bf2f(v.x); a1 += bf2f(v.y); a2 += bf2f(v.z); a3 += bf2f(v.w);
    }
    int c = en - st; if (c < 1) c = 1;
    float sc = 1.0f / (float)c;
    ushort4 outv;
    outv.x = f2bf(a0 * sc); outv.y = f2bf(a1 * sc);
    outv.z = f2bf(a2 * sc); outv.w = f2bf(a3 * sc);
    *(ushort4*)(pooled + (size_t)i * H_ + tid * 4) = outv;
}

// ---------------- final graph pooling ----------------
__global__ void scores_kernel(const float* __restrict__ ov,
                              const float* __restrict__ att_w,
                              const float* __restrict__ att_b,
                              float* __restrict__ scores)
{
    int gidx = blockIdx.x * blockDim.x + threadIdx.x;
    int obj = gidx >> 6;
    int lane = threadIdx.x & 63;
    if (obj >= O_N) return;
    const float* r = ov + (size_t)obj * D_;
    float v = r[lane] * att_w[lane] + r[lane + 64] * att_w[lane + 64];
    #pragma unroll
    for (int off = 32; off; off >>= 1) v += __shfl_down(v, off);
    if (lane == 0) scores[obj] = v + att_b[0];
}

// one block per image: binary-search bounds in SORTED obj_to_img,
// then max / sum(exp) / weighted ov-sum, all block-local.
__global__ __launch_bounds__(256)
void seg_gvec_kernel(const float* __restrict__ scores, const float* __restrict__ ovf,
                     const int* __restrict__ obj_to_img, float* __restrict__ gvec)
{
    __shared__ float red[256];
    __shared__ float sm, sz;
    int g = blockIdx.x, tid = threadIdx.x;
    int lo = 0, hi = O_N;
    while (lo < hi) { int mid = (lo + hi) >> 1; if (obj_to_img[mid] < g) lo = mid + 1; else hi = mid; }
    int st = lo;
    hi = O_N;
    while (lo < hi) { int mid = (lo + hi) >> 1; if (obj_to_img[mid] <= g) lo = mid + 1; else hi = mid; }
    int en = lo;

    float lm = -1e30f;
    for (int i = st + tid; i < en; i += 256) lm = fmaxf(lm, scores[i]);
    red[tid] = lm; __syncthreads();
    for (int s = 128; s; s >>= 1) { if (tid < s) red[tid] = fmaxf(red[tid], red[tid + s]); __syncthreads(); }
    if (tid == 0) sm = red[0];
    __syncthreads();
    float m = sm;

    float lz = 0.f;
    for (int i = st + tid; i < en; i += 256) lz += expf(scores[i] - m);
    red[tid] = lz; __syncthreads();
    for (int s = 128; s; s >>= 1) { if (tid < s) red[tid] += red[tid + s]; __syncthreads(); }
    if (tid == 0) sz = fmaxf(red[0], 1e-30f);
    __syncthreads();
    float invz = 1.0f / sz;

    int d = tid & 127, half = tid >> 7;
    float acc = 0.f;
    for (int i = st + half; i < en; i += 2)
        acc += expf(scores[i] - m) * ovf[(size_t)i * D_ + d];
    red[tid] = acc; __syncthreads();
    if (tid < 128) gvec[(size_t)g * D_ + tid] = (red[tid] + red[tid + 128]) * invz;
}

__global__ void output_kernel(const float* __restrict__ ov, const float* __restrict__ gvec,
                              const int* __restrict__ obj_to_img, float* __restrict__ out)
{
    int idx = blockIdx.x * blockDim.x + threadIdx.x;
    if (idx >= O_N * 256) return;
    int i = idx >> 8, d = idx & 255;
    out[idx] = (d < 128) ? ov[(size_t)i * D_ + d]
                         : gvec[obj_to_img[i] * D_ + (d - 128)];
}

// ---------------- host launch ----------------
extern "C" void kernel_launch(void* const* d_in, const int* in_sizes, int n_in,
                              void* d_out, int out_size, void* d_ws, size_t ws_size,
                              hipStream_t stream)
{
    const int*   objs       = (const int*)d_in[0];
    const int*   triples    = (const int*)d_in[1];
    const int*   obj_to_img = (const int*)d_in[2];
    const float* obj_emb    = (const float*)d_in[3];
    const float* pred_emb   = (const float*)d_in[4];
    const float* n1w1       = (const float*)d_in[5];
    const float* n1b1       = (const float*)d_in[6];
    const float* n1w2       = (const float*)d_in[7];
    const float* n1b2       = (const float*)d_in[8];
    const float* n2w1       = (const float*)d_in[9];
    const float* n2b1       = (const float*)d_in[10];
    const float* n2w2       = (const float*)d_in[11];
    const float* n2b2       = (const float*)d_in[12];
    const float* att_w      = (const float*)d_in[13];
    const float* att_b      = (const float*)d_in[14];
    float* out = (float*)d_out;

    char* p = (char*)d_ws;
    auto carve = [&](size_t bytes) -> char* {
        char* r = p; p += (bytes + 255) & ~(size_t)255; return r;
    };
    ushort_t* w1t     = (ushort_t*)carve((size_t)L_ * 512 * 384 * 2);
    ushort_t* w2t     = (ushort_t*)carve((size_t)L_ * 1152 * 512 * 2);
    ushort_t* w3t     = (ushort_t*)carve((size_t)L_ * 512 * 512 * 2);
    ushort_t* w4t     = (ushort_t*)carve((size_t)L_ * 128 * 512 * 2);
    ushort_t* ovbA    = (ushort_t*)carve((size_t)O_N * D_ * 2);
    ushort_t* ovbB    = (ushort_t*)carve((size_t)O_N * D_ * 2);
    ushort_t* predb   = (ushort_t*)carve((size_t)NPRED * D_ * 2);
    ushort_t* hiddenb = (ushort_t*)carve((size_t)T_N * H_ * 2);
    ushort_t* newtb   = (ushort_t*)carve((size_t)T_N * NT_ * 2);
    ushort_t* pooledb = (ushort_t*)carve((size_t)O_N * H_ * 2);
    float*    ovf     = (float*)carve((size_t)O_N * D_ * 4);
    float*    scores  = (float*)carve((size_t)O_N * 4);
    float*    gvec    = (float*)carve((size_t)G_ * D_ * 4);
    int*      cnt     = (int*)carve((size_t)O_N * 4);
    int*      off     = (int*)carve((size_t)(O_N + 1) * 4);
    int*      cursor  = (int*)carve((size_t)O_N * 4);
    int*      entries = (int*)carve((size_t)2 * T_N * 4);

    // once-per-call pre-compute (fused) + CSR build
    precompute_kernel<<<8050, 256, 0, stream>>>(
        n1w1, n1w2, n2w1, n2w2, w1t, w2t, w3t, w4t,
        objs, obj_emb, pred_emb, ovbA, predb, cnt);
    hist_kernel<<<(T_N + 255) / 256, 256, 0, stream>>>(triples, cnt);
    scan_kernel<<<1, 256, 0, stream>>>(cnt, off, cursor);
    fill_kernel<<<(T_N + 255) / 256, 256, 0, stream>>>(triples, cursor, entries);

    ushort_t* ovcur = ovbA;
    ushort_t* ovnxt = ovbB;

    const int MT256 = (T_N + 255) / 256;   // 79 M-tiles for the big GEMMs

    for (int l = 0; l < L_; ++l) {
        const ushort_t* Pl = (l == 0) ? predb : (newtb + H_);
        int pstr = (l == 0) ? D_ : NT_;
        int pmap = (l == 0) ? 1 : 0;

        // GEMM1: hidden = relu(concat(ov[s],pv,ov[o]) @ n1w1 + b1)   [20000 x 384 x 512]
        mfma_gemm<256, 1, 0><<<MT256 * 4, 512, 0, stream>>>(
            nullptr, w1t + (size_t)l * 512 * 384, n1b1 + (size_t)l * H_,
            hiddenb, nullptr, T_N, 512, 384, H_, 4,
            triples, ovcur, Pl, pstr, pmap);

        // GEMM2: new_t = relu(hidden @ n1w2 + b2)                    [20000 x 512 x 1152]
        mfma_gemm<256, 0, 0><<<MT256 * 9, 512, 0, stream>>>(
            hiddenb, w2t + (size_t)l * 1152 * 512, n1b2 + (size_t)l * NT_,
            newtb, nullptr, T_N, NT_, 512, NT_, 9,
            nullptr, nullptr, nullptr, 0, 0);

        // scatter-mean via CSR gather
        pooled_kernel<<<O_N, 128, 0, stream>>>(newtb, entries, off, pooledb);

        // GEMM3: h2 = relu(pooled @ n2w1 + b1)                       [5000 x 512 x 512]
        mfma_gemm<128, 0, 0><<<40 * 4, 256, 0, stream>>>(
            pooledb, w3t + (size_t)l * 512 * 512, n2b1 + (size_t)l * H_,
            hiddenb, nullptr, O_N, 512, 512, H_, 4,
            nullptr, nullptr, nullptr, 0, 0);

        // GEMM4: new_ov = relu(h2 @ n2w2 + b2)                       [5000 x 128 x 512]
        if (l < L_ - 1) {
            mfma_gemm<128, 0, 0><<<40 * 1, 256, 0, stream>>>(
                hiddenb, w4t + (size_t)l * 128 * 512, n2b2 + (size_t)l * D_,
                ovnxt, nullptr, O_N, 128, 512, D_, 1,
                nullptr, nullptr, nullptr, 0, 0);
        } else {
            mfma_gemm<128, 0, 1><<<40 * 1, 256, 0, stream>>>(
                hiddenb, w4t + (size_t)l * 128 * 512, n2b2 + (size_t)l * D_,
                ovnxt, ovf, O_N, 128, 512, D_, 1,
                nullptr, nullptr, nullptr, 0, 0);
        }

        ushort_t* tmp = ovcur; ovcur = ovnxt; ovnxt = tmp;
    }

    // graph pooling (fp32 ov from last GEMM4)
    scores_kernel<<<(O_N * 64 + 255) / 256, 256, 0, stream>>>(ovf, att_w, att_b, scores);
    seg_gvec_kernel<<<G_, 256, 0, stream>>>(scores, ovf, obj_to_img, gvec);
    output_kernel<<<(O_N * 256 + 255) / 256, 256, 0, stream>>>(ovf, gvec, obj_to_img, out);
}